// Round 5
// baseline (152.053 us; speedup 1.0000x reference)
//
#include <hip/hip_runtime.h>
#include <math.h>

#define NN 30000
#define DIST_C 5.0f
#define EPS_C 1e-6f
#define SCALE_C 0.17677669529663687f  // 1/sqrt(32)

// workspace float offsets (region below zeroed by memset each launch)
#define WS_ZSUM 0      // 32 f   [b*2+s]
#define WS_T    32     // 8192 f [b*512 + (s*8+h)*32 + d]
#define WS_CTR  8224   // 16 u32 per-batch arrival counters
#define WS_ZERO_BYTES ((8224 + 16) * 4)

__device__ __forceinline__ float silu(float x) { return x / (1.0f + expf(-x)); }

// edge[s][k] = sin(bw_k*x_s)/(x_s+eps); bw_k=(k+1)*bw0. Chebyshev recurrence:
// s_{k+1} = 2cos(th)*s_k - s_{k-1}.
__device__ __forceinline__ void bessel_edges(float bw0, float x0, float x1, float edge[2][8]) {
    float xs[2]; xs[0] = x0; xs[1] = x1;
#pragma unroll
    for (int s = 0; s < 2; ++s) {
        float x = xs[s];
        float inv = 1.0f / (x + EPS_C);
        float th = bw0 * x;
        float c2 = 2.0f * cosf(th);
        float skm1 = 0.0f;
        float sk = sinf(th);
#pragma unroll
        for (int k = 0; k < 8; ++k) {
            edge[s][k] = sk * inv;
            float nx = c2 * sk - skm1;
            skm1 = sk; sk = nx;
        }
    }
}

// One kernel. Grid = 16 * bpb blocks; block handles one 32-node tile of ONE
// batch (stride loop kept for bpb<64 fallback). b = blockIdx%16, m = blockIdx/16.
// launch_bounds(256,4): VGPR<=128 -> 4 blocks/CU -> 1024 blocks co-resident
// (LDS ~26KB allows 6/CU); per-batch atomic-counter barrier is deadlock-free.
__global__ __launch_bounds__(256, 4) void k_mega(
    const float* __restrict__ pos, const int* __restrict__ batch,
    const float* __restrict__ nf, const float* __restrict__ bw,
    const float* __restrict__ W1_kd, const float* __restrict__ W1_vd,
    const float* __restrict__ W1_kg, const float* __restrict__ W1_vg,
    const float* __restrict__ init_dummy, const float* __restrict__ Wq_dummy,
    const float* __restrict__ Wdot, const float* __restrict__ W2_kd,
    const float* __restrict__ W2_vd, const float* __restrict__ W2_kg,
    const float* __restrict__ W2_vg, const float* __restrict__ Wq_graph,
    float* __restrict__ ws, float* __restrict__ out, int bpb)
{
    __shared__ int bnd[17];
    __shared__ float Wdl[1024];
    __shared__ float qvec[32], qWl[32];
    __shared__ __align__(16) float Pk[256];
    __shared__ __align__(16) float Wc[1024];
    __shared__ float W1kd[64], W1vd[64], W1kg[64], W1vg[64];
    __shared__ __align__(16) float Fl[32 * 36];
    __shared__ float Lw[32 * 17];
    __shared__ float zred[8];
    __shared__ float zfin[2];
    __shared__ float Tl[512], part[512], dn[64];
    __shared__ __align__(16) float AKGl[512], AVGl[512];

    int t = threadIdx.x;
    int b = blockIdx.x & 15;
    int m = blockIdx.x >> 4;
    int li = t >> 3, g = t & 7;
    int lanebase = (t & 63) & 56;
    float bw0 = bw[0];

    // ---- stage 1: boundaries (batch sorted), weight staging, qvec (8-way parallel)
    if (t < 17) {
        int lo = 0, hi = NN;
        while (lo < hi) { int mid = (lo + hi) >> 1; if (batch[mid] < t) lo = mid + 1; else hi = mid; }
        bnd[t] = lo;
    }
    for (int i = t; i < 1024; i += 256) Wdl[i] = Wdot[i];
    if (t < 64) { W1kd[t] = W1_kd[t]; W1vd[t] = W1_vd[t]; W1kg[t] = W1_kg[t]; W1vg[t] = W1_vg[t]; }
    {   // qvec[o] = sum_d init_dummy[d] * Wq_dummy[d*32+o], 8 partials per output
        int o = t >> 3, j = t & 7;
        float acc = 0.f;
#pragma unroll
        for (int d = 0; d < 4; ++d) acc += init_dummy[j * 4 + d] * Wq_dummy[(j * 4 + d) * 32 + o];
        acc += __shfl_xor(acc, 1, 64);
        acc += __shfl_xor(acc, 2, 64);
        acc += __shfl_xor(acc, 4, 64);
        if (j == 0) qvec[o] = acc;
    }
    __syncthreads();
    int s0 = bnd[b], s1 = bnd[b + 1];
    int stride = bpb * 32;
    int base0 = s0 + m * 32;

    // ---- stage 2: prefetch my tile into regs; zminmax scan; qW (8-way)
    float4 fv4 = make_float4(0.f, 0.f, 0.f, 0.f);
    float zz = 0.f;
    {
        int cnt0 = s1 - base0; if (cnt0 > 32) cnt0 = 32;
        if (li < cnt0) {
            int n = base0 + li;
            fv4 = ((const float4*)nf)[n * 8 + g];
            zz = pos[3 * n + 2];
        }
    }
    {
        float zmn = 3.4e38f, zmx = -3.4e38f;
        for (int i = s0 + t; i < s1; i += 256) {
            float v = pos[3 * i + 2];
            zmn = fminf(zmn, v); zmx = fmaxf(zmx, v);
        }
#pragma unroll
        for (int off = 1; off < 64; off <<= 1) {
            zmn = fminf(zmn, __shfl_xor(zmn, off, 64));
            zmx = fmaxf(zmx, __shfl_xor(zmx, off, 64));
        }
        if ((t & 63) == 0) { zred[(t >> 6) * 2] = zmn; zred[(t >> 6) * 2 + 1] = zmx; }
    }
    {   // qW[o] = sum_e qvec[e] * Wdot[e*32+o]
        int o = t >> 3, j = t & 7;
        float acc = 0.f;
#pragma unroll
        for (int e = 0; e < 4; ++e) acc += qvec[j * 4 + e] * Wdl[(j * 4 + e) * 32 + o];
        acc += __shfl_xor(acc, 1, 64);
        acc += __shfl_xor(acc, 2, 64);
        acc += __shfl_xor(acc, 4, 64);
        if (j == 0) qWl[o] = acc;
    }
    __syncthreads();

    // ---- stage 3: zfin combine + Pk
    if (t == 0) {
        zfin[0] = fminf(fminf(zred[0], zred[2]), fminf(zred[4], zred[6]));
        zfin[1] = fmaxf(fmaxf(zred[1], zred[3]), fmaxf(zred[5], zred[7]));
    }
    {   // Pk[h][d] = sum_e W2_kd[h, d*32+e] * qW[e]
        int h = t >> 5, d = t & 31;
        float acc = 0.f;
        for (int e = 0; e < 32; ++e) acc += W2_kd[h * 1024 + d * 32 + e] * qWl[e];
        Pk[t] = acc;
    }
    __syncthreads();
    float zminb = zfin[0], zmaxb = zfin[1];

    // ---- phase A: my tile(s); first tile uses prefetched regs
    float edge[2][8];
    float tAcc0 = 0.f, tAcc1 = 0.f, zsA0 = 0.f, zsA1 = 0.f;
    int sh = t & 15, dp = t >> 4;
    int aIters = 0;
    for (int base = base0; base < s1; base += stride) {
        int cnt = s1 - base; if (cnt > 32) cnt = 32;
        bool valid = li < cnt;
        float4 f4; float zv;
        if (aIters == 0) { f4 = fv4; zv = zz; }
        else {
            f4 = make_float4(0.f, 0.f, 0.f, 0.f); zv = 0.f;
            if (valid) {
                int n = base + li;
                f4 = ((const float4*)nf)[n * 8 + g];
                zv = pos[3 * n + 2];
            }
        }
        if (valid) {
            ((float4*)(Fl + li * 36))[g] = f4;
            bessel_edges(bw0, zv - zminb + DIST_C, zmaxb + DIST_C - zv, edge);
            float up[8];
            const float4* Pk4 = (const float4*)Pk;
#pragma unroll
            for (int h = 0; h < 8; ++h) {
                float4 p = Pk4[h * 8 + g];
                up[h] = f4.x * p.x + f4.y * p.y + f4.z * p.z + f4.w * p.w;
            }
            float p0 = 0.f, p1 = 0.f;
#pragma unroll
            for (int k = 0; k < 8; ++k) {
                float w = W1kd[k * 8 + g];
                p0 += edge[0][k] * w; p1 += edge[1][k] * w;
            }
            float kd0 = silu(p0), kd1 = silu(p1);
            float sp0 = 0.f, sp1 = 0.f;
#pragma unroll
            for (int h = 0; h < 8; ++h) {
                sp0 += __shfl(kd0, lanebase + h, 64) * up[h];
                sp1 += __shfl(kd1, lanebase + h, 64) * up[h];
            }
#pragma unroll
            for (int mm = 1; mm < 8; mm <<= 1) {
                sp0 += __shfl_xor(sp0, mm, 64);
                sp1 += __shfl_xor(sp1, mm, 64);
            }
            float ev0 = expf(sp0 * SCALE_C);
            float ev1 = expf(sp1 * SCALE_C);
            if (g == 0) { zsA0 += ev0; zsA1 += ev1; }
            float q0 = 0.f, q1 = 0.f;
#pragma unroll
            for (int k = 0; k < 8; ++k) {
                float w = W1vd[k * 8 + g];
                q0 += edge[0][k] * w; q1 += edge[1][k] * w;
            }
            Lw[li * 17 + g] = ev0 * silu(q0);
            Lw[li * 17 + 8 + g] = ev1 * silu(q1);
        }
        __syncthreads();
        for (int i = 0; i < cnt; ++i) {   // outer-product reduce (all nodes batch b)
            float w = Lw[i * 17 + sh];
            float2 x = *(const float2*)(Fl + i * 36 + 2 * dp);
            tAcc0 += w * x.x; tAcc1 += w * x.y;
        }
        __syncthreads();
        ++aIters;
    }
    {
        float* Tb = ws + WS_T + b * 512 + sh * 32 + 2 * dp;
        atomicAdd(&Tb[0], tAcc0);
        atomicAdd(&Tb[1], tAcc1);
#pragma unroll
        for (int off = 1; off < 64; off <<= 1) {   // g!=0 lanes hold 0
            zsA0 += __shfl_xor(zsA0, off, 64);
            zsA1 += __shfl_xor(zsA1, off, 64);
        }
        if ((t & 63) == 0) { zred[(t >> 6) * 2] = zsA0; zred[(t >> 6) * 2 + 1] = zsA1; }
    }
    __syncthreads();
    if (t == 0) {
        atomicAdd(ws + WS_ZSUM + b * 2,     zred[0] + zred[2] + zred[4] + zred[6]);
        atomicAdd(ws + WS_ZSUM + b * 2 + 1, zred[1] + zred[3] + zred[5] + zred[7]);
    }
    __syncthreads();

    // ---- per-batch barrier (bpb blocks); compute Wc while waiting
    unsigned* ctru = (unsigned*)(ws + WS_CTR);
    if (t == 0) { __threadfence(); atomicAdd(&ctru[b], 1u); }
    for (int i = t; i < 1024; i += 256) {   // Wc = Wq_graph @ Wdot
        int d = i >> 5, e = i & 31;
        float acc = 0.f;
        for (int mm = 0; mm < 32; ++mm) acc += Wq_graph[d * 32 + mm] * Wdl[mm * 32 + e];
        Wc[i] = acc;
    }
    if (t == 0) {
        int guard = 0;
        while (__hip_atomic_load(&ctru[b], __ATOMIC_ACQUIRE, __HIP_MEMORY_SCOPE_AGENT)
               < (unsigned)bpb) {
            __builtin_amdgcn_s_sleep(8);
            if (++guard > (1 << 26)) break;   // defensive; never expected
        }
    }
    __syncthreads();

    // ---- phase B (redundant per block; AKG/AVG stay in LDS)
    Tl[t]       = __hip_atomic_load(ws + WS_T + b * 512 + t,       __ATOMIC_RELAXED, __HIP_MEMORY_SCOPE_AGENT);
    Tl[256 + t] = __hip_atomic_load(ws + WS_T + b * 512 + 256 + t, __ATOMIC_RELAXED, __HIP_MEMORY_SCOPE_AGENT);
    if (t == 0) {
        zfin[0] = __hip_atomic_load(ws + WS_ZSUM + b * 2,     __ATOMIC_RELAXED, __HIP_MEMORY_SCOPE_AGENT);
        zfin[1] = __hip_atomic_load(ws + WS_ZSUM + b * 2 + 1, __ATOMIC_RELAXED, __HIP_MEMORY_SCOPE_AGENT);
    }
    __syncthreads();
    {
        int h = t >> 5, e = t & 31;
        float a0 = 0.f, a1 = 0.f;
        for (int d = 0; d < 32; ++d) {
            float w2 = W2_vd[h * 1024 + d * 32 + e];
            a0 += Tl[h * 32 + d] * w2;
            a1 += Tl[256 + h * 32 + d] * w2;
        }
        part[t] = a0; part[256 + t] = a1;
    }
    __syncthreads();
    if (t < 64) {
        int s = t >> 5, dd = t & 31;
        float acc = 0.f;
        for (int h = 0; h < 8; ++h) acc += part[s * 256 + h * 32 + dd];
        dn[t] = init_dummy[dd] + acc / zfin[s];
    }
    __syncthreads();
    {
        int h = t >> 5, e = t & 31;
        float ak0 = 0.f, av0 = 0.f, ak1 = 0.f, av1 = 0.f;
        for (int d = 0; d < 32; ++d) {
            float w2k = W2_kg[h * 1024 + d * 32 + e];
            float w2v = W2_vg[h * 1024 + d * 32 + e];
            ak0 += dn[d] * w2k;      av0 += dn[d] * w2v;
            ak1 += dn[32 + d] * w2k; av1 += dn[32 + d] * w2v;
        }
        AKGl[t] = ak0; AKGl[256 + t] = ak1;
        AVGl[t] = av0; AVGl[256 + t] = av1;
    }
    __syncthreads();

    // ---- phase C: per-node output; single-tile blocks reuse regs + LDS from A
    const float4* Ak4 = (const float4*)AKGl;
    const float4* Av4 = (const float4*)AVGl;
    const float4* Wc4 = (const float4*)Wc;
    bool firstC = true;
    for (int base = base0; base < s1; base += stride) {
        int cnt = s1 - base; if (cnt > 32) cnt = 32;
        bool valid = li < cnt;
        bool useCache = firstC && (aIters == 1);
        float4 f4 = fv4;
        if (!useCache) {
            float zv = 0.f;
            f4 = make_float4(0.f, 0.f, 0.f, 0.f);
            if (valid) {
                int n = base + li;
                f4 = ((const float4*)nf)[n * 8 + g];
                zv = pos[3 * n + 2];
                ((float4*)(Fl + li * 36))[g] = f4;
            }
            __syncthreads();
            if (valid)
                bessel_edges(bw0, zv - zminb + DIST_C, zmaxb + DIST_C - zv, edge);
        }
        if (valid) {
            float sk0, sk1, sv0, sv1;
            {
                float pk0 = 0.f, pk1 = 0.f, pv0 = 0.f, pv1 = 0.f;
#pragma unroll
                for (int k = 0; k < 8; ++k) {
                    float wk = W1kg[k * 8 + g];
                    float wv = W1vg[k * 8 + g];
                    pk0 += edge[0][k] * wk; pk1 += edge[1][k] * wk;
                    pv0 += edge[0][k] * wv; pv1 += edge[1][k] * wv;
                }
                sk0 = silu(pk0); sk1 = silu(pk1);
                sv0 = silu(pv0); sv1 = silu(pv1);
            }
            float4 q4 = make_float4(0.f, 0.f, 0.f, 0.f);
            const float* myF = Fl + li * 36;
#pragma unroll
            for (int d = 0; d < 32; ++d) {
                float fd = myF[d];
                float4 w = Wc4[d * 8 + g];
                q4.x += fd * w.x; q4.y += fd * w.y; q4.z += fd * w.z; q4.w += fd * w.w;
            }
            float p0 = 0.f, p1 = 0.f;
#pragma unroll
            for (int h = 0; h < 8; ++h) {
                float4 a0 = Ak4[h * 8 + g];
                float4 a1 = Ak4[64 + h * 8 + g];
                float d0 = q4.x * a0.x + q4.y * a0.y + q4.z * a0.z + q4.w * a0.w;
                float d1 = q4.x * a1.x + q4.y * a1.y + q4.z * a1.z + q4.w * a1.w;
                p0 += __shfl(sk0, lanebase + h, 64) * d0;
                p1 += __shfl(sk1, lanebase + h, 64) * d1;
            }
#pragma unroll
            for (int mm = 1; mm < 8; mm <<= 1) {
                p0 += __shfl_xor(p0, mm, 64);
                p1 += __shfl_xor(p1, mm, 64);
            }
            float sg0 = p0 * SCALE_C, sg1 = p1 * SCALE_C;
            float mx = fmaxf(sg0, sg1);
            float e0 = expf(sg0 - mx), e1 = expf(sg1 - mx);
            float inv = 1.0f / (e0 + e1);
            float ag0 = e0 * inv, ag1 = e1 * inv;
            float4 x4 = f4;
#pragma unroll
            for (int h = 0; h < 8; ++h) {
                float w0 = ag0 * __shfl(sv0, lanebase + h, 64);
                float w1 = ag1 * __shfl(sv1, lanebase + h, 64);
                float4 a0 = Av4[h * 8 + g];
                float4 a1 = Av4[64 + h * 8 + g];
                x4.x += w0 * a0.x + w1 * a1.x;
                x4.y += w0 * a0.y + w1 * a1.y;
                x4.z += w0 * a0.z + w1 * a1.z;
                x4.w += w0 * a0.w + w1 * a1.w;
            }
            int n = base + li;
            ((float4*)out)[n * 8 + g] = x4;
        }
        firstC = false;
        __syncthreads();
    }
}

extern "C" void kernel_launch(void* const* d_in, const int* in_sizes, int n_in,
                              void* d_out, int out_size, void* d_ws, size_t ws_size,
                              hipStream_t stream) {
    const float* pos        = (const float*)d_in[0];
    const float* nf         = (const float*)d_in[1];
    const int*   batch      = (const int*)d_in[2];
    const float* bw         = (const float*)d_in[3];
    const float* init_dummy = (const float*)d_in[4];
    const float* Wq_dummy   = (const float*)d_in[5];
    const float* Wq_graph   = (const float*)d_in[6];
    const float* Wdot       = (const float*)d_in[7];
    const float* W1_kd      = (const float*)d_in[8];
    const float* W2_kd      = (const float*)d_in[9];
    const float* W1_vd      = (const float*)d_in[10];
    const float* W2_vd      = (const float*)d_in[11];
    const float* W1_kg      = (const float*)d_in[12];
    const float* W2_kg      = (const float*)d_in[13];
    const float* W1_vg      = (const float*)d_in[14];
    const float* W2_vg      = (const float*)d_in[15];
    float* ws  = (float*)d_ws;
    float* out = (float*)d_out;

    // capture-safe host query, cached: pick blocks-per-batch so the whole grid
    // is guaranteed co-resident (spin-barrier safety).
    static int bpb_cached = -1;
    if (bpb_cached < 0) {
        int maxb = 0;
        hipError_t e = hipOccupancyMaxActiveBlocksPerMultiprocessor(
            &maxb, reinterpret_cast<const void*>(k_mega), 256, 0);
        if (e != hipSuccess) maxb = 2;
        bpb_cached = (maxb >= 4) ? 64 : ((maxb >= 2) ? 32 : 16);
    }

    hipMemsetAsync(ws, 0, WS_ZERO_BYTES, stream);
    hipLaunchKernelGGL(k_mega, dim3(16 * bpb_cached), dim3(256), 0, stream,
                       pos, batch, nf, bw, W1_kd, W1_vd, W1_kg, W1_vg,
                       init_dummy, Wq_dummy, Wdot, W2_kd, W2_vd, W2_kg, W2_vg, Wq_graph,
                       ws, out, bpb_cached);
}

// Round 6
// 123.964 us; speedup vs baseline: 1.2266x; 1.2266x over previous
//
#include <hip/hip_runtime.h>
#include <math.h>

#define NN 30000
#define DIST_C 5.0f
#define EPS_C 1e-6f
#define SCALE_C 0.17677669529663687f  // 1/sqrt(32)

// workspace float offsets
#define WS_ZMIN 0      // 16 f (plain floats)
#define WS_ZMAX 16     // 16 f
#define WS_ZSUM 32     // 32 f  [b*2+s]
#define WS_T    64     // 8192 f [b*512 + (s*8+h)*32 + d]
#define WS_PK   8256   // 256 f [h*32+d]
#define WS_WC   8512   // 1024 f [d*32+e]

__device__ __forceinline__ float silu(float x) { return x / (1.0f + expf(-x)); }

// edge[s][k] = sin(bw_k*x_s)/(x_s+eps); bw_k=(k+1)*bw0. Chebyshev recurrence:
// s_{k+1} = 2cos(th)*s_k - s_{k-1}.
__device__ __forceinline__ void bessel_edges(float bw0, float x0, float x1, float edge[2][8]) {
    float xs[2]; xs[0] = x0; xs[1] = x1;
#pragma unroll
    for (int s = 0; s < 2; ++s) {
        float x = xs[s];
        float inv = 1.0f / (x + EPS_C);
        float th = bw0 * x;
        float c2 = 2.0f * cosf(th);
        float skm1 = 0.0f;
        float sk = sinf(th);
#pragma unroll
        for (int k = 0; k < 8; ++k) {
            edge[s][k] = sk * inv;
            float nx = c2 * sk - skm1;
            skm1 = sk; sk = nx;
        }
    }
}

// ---------------------------------------------------------------- K1: pre
// blocks 0-15: per-batch zminmax (binary-search bounds + scan, plain writes)
// block 16: Pk chain; block 17: Wc; blocks 18-33: zero T + ZSUM.
__global__ __launch_bounds__(256) void k_pre(const float* __restrict__ pos,
                                             const int* __restrict__ batch,
                                             const float* __restrict__ init_dummy,
                                             const float* __restrict__ Wq_dummy,
                                             const float* __restrict__ Wdot,
                                             const float* __restrict__ W2_kd,
                                             const float* __restrict__ Wq_graph,
                                             float* __restrict__ ws) {
    int t = threadIdx.x, blk = blockIdx.x;
    if (blk < 16) {
        __shared__ int bnd2[2];
        __shared__ float r[8];
        if (t < 2) {
            int target = blk + t;
            int lo = 0, hi = NN;
            while (lo < hi) { int mid = (lo + hi) >> 1; if (batch[mid] < target) lo = mid + 1; else hi = mid; }
            bnd2[t] = lo;
        }
        __syncthreads();
        int s0 = bnd2[0], s1 = bnd2[1];
        float zmn = 3.4e38f, zmx = -3.4e38f;
        for (int i = s0 + t; i < s1; i += 256) {
            float v = pos[3 * i + 2];
            zmn = fminf(zmn, v); zmx = fmaxf(zmx, v);
        }
#pragma unroll
        for (int off = 1; off < 64; off <<= 1) {
            zmn = fminf(zmn, __shfl_xor(zmn, off, 64));
            zmx = fmaxf(zmx, __shfl_xor(zmx, off, 64));
        }
        if ((t & 63) == 0) { r[(t >> 6) * 2] = zmn; r[(t >> 6) * 2 + 1] = zmx; }
        __syncthreads();
        if (t == 0) {
            ws[WS_ZMIN + blk] = fminf(fminf(r[0], r[2]), fminf(r[4], r[6]));
            ws[WS_ZMAX + blk] = fmaxf(fmaxf(r[1], r[3]), fmaxf(r[5], r[7]));
        }
    } else if (blk == 16) {
        __shared__ float qv[32], qW[32];
        if (t < 32) {
            float acc = 0.f;
            for (int d = 0; d < 32; ++d) acc += init_dummy[d] * Wq_dummy[d * 32 + t];
            qv[t] = acc;
        }
        __syncthreads();
        if (t < 32) {
            float acc = 0.f;
            for (int e = 0; e < 32; ++e) acc += qv[e] * Wdot[e * 32 + t];
            qW[t] = acc;
        }
        __syncthreads();
        int h = t >> 5, d = t & 31;
        float acc = 0.f;
        for (int e = 0; e < 32; ++e) acc += W2_kd[h * 1024 + d * 32 + e] * qW[e];
        ws[WS_PK + t] = acc;
    } else if (blk == 17) {
        for (int i = t; i < 1024; i += 256) {
            int d = i >> 5, e = i & 31;
            float acc = 0.f;
            for (int m = 0; m < 32; ++m) acc += Wq_graph[d * 32 + m] * Wdot[m * 32 + e];
            ws[WS_WC + i] = acc;
        }
    } else {
        int idx = blk - 18;
        ws[WS_T + idx * 512 + t] = 0.f;
        ws[WS_T + idx * 512 + 256 + t] = 0.f;
        if (idx == 0 && t < 32) ws[WS_ZSUM + t] = 0.f;
    }
}

// ---------------------------------------------------------------- K2: phase 1
// 8 threads per node: t = li*8 + g. Fl row stride 36 floats; Lw row stride 17.
__global__ __launch_bounds__(256) void k_phase1(const float* __restrict__ pos,
                                                const int* __restrict__ batch,
                                                const float* __restrict__ nf,
                                                const float* __restrict__ bw,
                                                const float* __restrict__ W1_kd,
                                                const float* __restrict__ W1_vd,
                                                float* __restrict__ ws) {
    __shared__ __align__(16) float Fl[32 * 36];
    __shared__ float Lw[32 * 17];
    __shared__ int   Lb[32];
    __shared__ __align__(16) float Pk[256];
    __shared__ float W1kd[64], W1vd[64], zsl[32];
    int t = threadIdx.x;
    if (t < 64) { W1kd[t] = W1_kd[t]; W1vd[t] = W1_vd[t]; }
    Pk[t] = ws[WS_PK + t];
    if (t < 32) zsl[t] = 0.f;

    int li = t >> 3, g = t & 7;
    int n0 = blockIdx.x * 32;
    int n = n0 + li;
    bool valid = n < NN;
    float4 fv4 = make_float4(0.f, 0.f, 0.f, 0.f);
    int b = 0;
    if (valid) {
        b = batch[n];
        fv4 = ((const float4*)nf)[n * 8 + g];
        ((float4*)(Fl + li * 36))[g] = fv4;
        if (g == 0) Lb[li] = b;
    } else {
        if (g == 0) Lb[li] = -1;
    }
    __syncthreads();

    if (valid) {
        float z = pos[3 * n + 2];
        float zminb = ws[WS_ZMIN + b];
        float zmaxb = ws[WS_ZMAX + b];
        float edge[2][8];
        bessel_edges(bw[0], z - zminb + DIST_C, zmaxb + DIST_C - z, edge);

        float up[8];
        const float4* Pk4 = (const float4*)Pk;
#pragma unroll
        for (int h = 0; h < 8; ++h) {
            float4 p = Pk4[h * 8 + g];
            up[h] = fv4.x * p.x + fv4.y * p.y + fv4.z * p.z + fv4.w * p.w;
        }
        float kd0, kd1;
        {
            float p0 = 0.f, p1 = 0.f;
#pragma unroll
            for (int k = 0; k < 8; ++k) {
                float w = W1kd[k * 8 + g];
                p0 += edge[0][k] * w;
                p1 += edge[1][k] * w;
            }
            kd0 = silu(p0); kd1 = silu(p1);
        }
        int lanebase = (t & 63) & 56;
        float sp0 = 0.f, sp1 = 0.f;
#pragma unroll
        for (int h = 0; h < 8; ++h) {
            sp0 += __shfl(kd0, lanebase + h, 64) * up[h];
            sp1 += __shfl(kd1, lanebase + h, 64) * up[h];
        }
#pragma unroll
        for (int m = 1; m < 8; m <<= 1) {
            sp0 += __shfl_xor(sp0, m, 64);
            sp1 += __shfl_xor(sp1, m, 64);
        }
        float ev0 = expf(sp0 * SCALE_C);
        float ev1 = expf(sp1 * SCALE_C);
        if (g == 0) {
            atomicAdd(&zsl[b * 2 + 0], ev0);
            atomicAdd(&zsl[b * 2 + 1], ev1);
        }
        float q0 = 0.f, q1 = 0.f;
#pragma unroll
        for (int k = 0; k < 8; ++k) {
            float w = W1vd[k * 8 + g];
            q0 += edge[0][k] * w;
            q1 += edge[1][k] * w;
        }
        Lw[li * 17 + g]     = ev0 * silu(q0);
        Lw[li * 17 + 8 + g] = ev1 * silu(q1);
    }
    __syncthreads();
    if (t < 32 && zsl[t] != 0.f) atomicAdd(&ws[WS_ZSUM + t], zsl[t]);

    // segment outer-product reduce: T[b][sh][d] += Lw[i][sh] * Fl[i][d]
    int count = NN - n0; if (count > 32) count = 32;
    int bf = Lb[0], bl = Lb[count - 1];
    int sh = t & 15, dp = t >> 4;
    for (int b2 = bf; b2 <= bl; ++b2) {
        float a0 = 0.f, a1 = 0.f;
        for (int i = 0; i < count; ++i) {
            if (Lb[i] != b2) continue;
            float w = Lw[i * 17 + sh];
            float2 x = *(const float2*)(Fl + i * 36 + 2 * dp);
            a0 += w * x.x;
            a1 += w * x.y;
        }
        float* Tb = ws + WS_T + b2 * 512 + sh * 32 + 2 * dp;
        atomicAdd(&Tb[0], a0);
        atomicAdd(&Tb[1], a1);
    }
}

// ---------------------------------------------------------------- K3: B (redundant, in-LDS) + final
// T is complete at kernel entry (previous kernel boundary). Each block computes
// dummy_new -> AKG/AVG for the (<=2) batches its 32-node tile touches, then C.
__global__ __launch_bounds__(256) void k_fin(const float* __restrict__ pos,
                                             const int* __restrict__ batch,
                                             const float* __restrict__ nf,
                                             const float* __restrict__ bw,
                                             const float* __restrict__ W1_kg,
                                             const float* __restrict__ W1_vg,
                                             const float* __restrict__ init_dummy,
                                             const float* __restrict__ W2_vd,
                                             const float* __restrict__ W2_kg,
                                             const float* __restrict__ W2_vg,
                                             const float* __restrict__ ws,
                                             float* __restrict__ out) {
    __shared__ __align__(16) float Wc[1024];
    __shared__ __align__(16) float Fl[32 * 36];
    __shared__ int   Lb[32];
    __shared__ float W1kg[64], W1vg[64];
    __shared__ float Tl[2][512];
    __shared__ float part[2][512];
    __shared__ float dn[2][64];           // [slot][s*32+d]
    __shared__ __align__(16) float AK[2][512], AV[2][512];

    int t = threadIdx.x;
    int li = t >> 3, g = t & 7;
    int lanebase = (t & 63) & 56;
    for (int i = t; i < 1024; i += 256) Wc[i] = ws[WS_WC + i];
    if (t < 64) { W1kg[t] = W1_kg[t]; W1vg[t] = W1_vg[t]; }

    int n0 = blockIdx.x * 32;
    int n = n0 + li;
    int count = NN - n0; if (count > 32) count = 32;
    bool valid = li < count;
    float4 fv4 = make_float4(0.f, 0.f, 0.f, 0.f);
    float z = 0.f;
    int b = 0;
    if (valid) {
        b = batch[n];
        fv4 = ((const float4*)nf)[n * 8 + g];
        ((float4*)(Fl + li * 36))[g] = fv4;
        z = pos[3 * n + 2];
        if (g == 0) Lb[li] = b;
    }
    __syncthreads();
    int bf = Lb[0], bl = Lb[count - 1];   // tile spans at most 2 batches

    // stage T for both slots (slot1 duplicates slot0 when bf==bl)
    Tl[0][t]       = ws[WS_T + bf * 512 + t];
    Tl[0][256 + t] = ws[WS_T + bf * 512 + 256 + t];
    Tl[1][t]       = ws[WS_T + bl * 512 + t];
    Tl[1][256 + t] = ws[WS_T + bl * 512 + 256 + t];
    __syncthreads();
    {   // part[j][s*256 + h*32+e] = sum_d Tl[j][s*256 + h*32+d] * W2_vd[h,d*32+e]
        int h = t >> 5, e = t & 31;
        float a00 = 0.f, a01 = 0.f, a10 = 0.f, a11 = 0.f;
        for (int d = 0; d < 32; ++d) {
            float w2 = W2_vd[h * 1024 + d * 32 + e];
            a00 += Tl[0][h * 32 + d] * w2;
            a01 += Tl[0][256 + h * 32 + d] * w2;
            a10 += Tl[1][h * 32 + d] * w2;
            a11 += Tl[1][256 + h * 32 + d] * w2;
        }
        part[0][t] = a00; part[0][256 + t] = a01;
        part[1][t] = a10; part[1][256 + t] = a11;
    }
    __syncthreads();
    if (t < 64) {
        int s = t >> 5, dd = t & 31;
        float acc0 = 0.f, acc1 = 0.f;
        for (int h = 0; h < 8; ++h) {
            acc0 += part[0][s * 256 + h * 32 + dd];
            acc1 += part[1][s * 256 + h * 32 + dd];
        }
        float id = init_dummy[dd];
        dn[0][t] = id + acc0 / ws[WS_ZSUM + bf * 2 + s];
        dn[1][t] = id + acc1 / ws[WS_ZSUM + bl * 2 + s];
    }
    __syncthreads();
    {   // AK/AV[j][s*256 + h*32+e] = sum_d dn[j][s*32+d] * W2_{kg,vg}[h,d*32+e]
        int h = t >> 5, e = t & 31;
        float k00 = 0.f, k01 = 0.f, k10 = 0.f, k11 = 0.f;
        float v00 = 0.f, v01 = 0.f, v10 = 0.f, v11 = 0.f;
        for (int d = 0; d < 32; ++d) {
            float w2k = W2_kg[h * 1024 + d * 32 + e];
            float w2v = W2_vg[h * 1024 + d * 32 + e];
            k00 += dn[0][d] * w2k;      v00 += dn[0][d] * w2v;
            k01 += dn[0][32 + d] * w2k; v01 += dn[0][32 + d] * w2v;
            k10 += dn[1][d] * w2k;      v10 += dn[1][d] * w2v;
            k11 += dn[1][32 + d] * w2k; v11 += dn[1][32 + d] * w2v;
        }
        AK[0][t] = k00; AK[0][256 + t] = k01;
        AK[1][t] = k10; AK[1][256 + t] = k11;
        AV[0][t] = v00; AV[0][256 + t] = v01;
        AV[1][t] = v10; AV[1][256 + t] = v11;
    }
    __syncthreads();

    if (!valid) return;
    int slot = (b == bf) ? 0 : 1;
    const float4* Ak4 = (const float4*)AK[slot];
    const float4* Av4 = (const float4*)AV[slot];
    const float4* Wc4 = (const float4*)Wc;

    float zminb = ws[WS_ZMIN + b];
    float zmaxb = ws[WS_ZMAX + b];
    float edge[2][8];
    bessel_edges(bw[0], z - zminb + DIST_C, zmaxb + DIST_C - z, edge);

    float sk0, sk1, sv0, sv1;
    {
        float pk0 = 0.f, pk1 = 0.f, pv0 = 0.f, pv1 = 0.f;
#pragma unroll
        for (int k = 0; k < 8; ++k) {
            float wk = W1kg[k * 8 + g];
            float wv = W1vg[k * 8 + g];
            pk0 += edge[0][k] * wk; pk1 += edge[1][k] * wk;
            pv0 += edge[0][k] * wv; pv1 += edge[1][k] * wv;
        }
        sk0 = silu(pk0); sk1 = silu(pk1);
        sv0 = silu(pv0); sv1 = silu(pv1);
    }
    float4 q4 = make_float4(0.f, 0.f, 0.f, 0.f);
    const float* myF = Fl + li * 36;
#pragma unroll
    for (int d = 0; d < 32; ++d) {
        float fd = myF[d];
        float4 w = Wc4[d * 8 + g];
        q4.x += fd * w.x; q4.y += fd * w.y; q4.z += fd * w.z; q4.w += fd * w.w;
    }
    float p0 = 0.f, p1 = 0.f;
#pragma unroll
    for (int h = 0; h < 8; ++h) {
        float4 a0 = Ak4[h * 8 + g];
        float4 a1 = Ak4[64 + h * 8 + g];
        float d0 = q4.x * a0.x + q4.y * a0.y + q4.z * a0.z + q4.w * a0.w;
        float d1 = q4.x * a1.x + q4.y * a1.y + q4.z * a1.z + q4.w * a1.w;
        p0 += __shfl(sk0, lanebase + h, 64) * d0;
        p1 += __shfl(sk1, lanebase + h, 64) * d1;
    }
#pragma unroll
    for (int m = 1; m < 8; m <<= 1) {
        p0 += __shfl_xor(p0, m, 64);
        p1 += __shfl_xor(p1, m, 64);
    }
    float sg0 = p0 * SCALE_C, sg1 = p1 * SCALE_C;
    float mx = fmaxf(sg0, sg1);
    float e0 = expf(sg0 - mx), e1 = expf(sg1 - mx);
    float inv = 1.0f / (e0 + e1);
    float ag0 = e0 * inv, ag1 = e1 * inv;

    float4 x4 = fv4;
#pragma unroll
    for (int h = 0; h < 8; ++h) {
        float w0 = ag0 * __shfl(sv0, lanebase + h, 64);
        float w1 = ag1 * __shfl(sv1, lanebase + h, 64);
        float4 a0 = Av4[h * 8 + g];
        float4 a1 = Av4[64 + h * 8 + g];
        x4.x += w0 * a0.x + w1 * a1.x;
        x4.y += w0 * a0.y + w1 * a1.y;
        x4.z += w0 * a0.z + w1 * a1.z;
        x4.w += w0 * a0.w + w1 * a1.w;
    }
    ((float4*)out)[n * 8 + g] = x4;
}

extern "C" void kernel_launch(void* const* d_in, const int* in_sizes, int n_in,
                              void* d_out, int out_size, void* d_ws, size_t ws_size,
                              hipStream_t stream) {
    const float* pos        = (const float*)d_in[0];
    const float* nf         = (const float*)d_in[1];
    const int*   batch      = (const int*)d_in[2];
    const float* bw         = (const float*)d_in[3];
    const float* init_dummy = (const float*)d_in[4];
    const float* Wq_dummy   = (const float*)d_in[5];
    const float* Wq_graph   = (const float*)d_in[6];
    const float* Wdot       = (const float*)d_in[7];
    const float* W1_kd      = (const float*)d_in[8];
    const float* W2_kd      = (const float*)d_in[9];
    const float* W1_vd      = (const float*)d_in[10];
    const float* W2_vd      = (const float*)d_in[11];
    const float* W1_kg      = (const float*)d_in[12];
    const float* W2_kg      = (const float*)d_in[13];
    const float* W1_vg      = (const float*)d_in[14];
    const float* W2_vg      = (const float*)d_in[15];
    float* ws  = (float*)d_ws;
    float* out = (float*)d_out;

    int nblk = (NN + 31) / 32;   // 938
    hipLaunchKernelGGL(k_pre, dim3(34), dim3(256), 0, stream,
                       pos, batch, init_dummy, Wq_dummy, Wdot, W2_kd, Wq_graph, ws);
    hipLaunchKernelGGL(k_phase1, dim3(nblk), dim3(256), 0, stream,
                       pos, batch, nf, bw, W1_kd, W1_vd, ws);
    hipLaunchKernelGGL(k_fin, dim3(nblk), dim3(256), 0, stream,
                       pos, batch, nf, bw, W1_kg, W1_vg, init_dummy,
                       W2_vd, W2_kg, W2_vg, ws, out);
}